// Round 8
// baseline (95.969 us; speedup 1.0000x reference)
//
#include <hip/hip_runtime.h>

#define B_   2
#define N_   512
#define DM_  1024
#define H_   16
#define LAM_ 0.1f

typedef __attribute__((ext_vector_type(8))) short bf16x8;
typedef __attribute__((ext_vector_type(4))) float f32x4;
typedef unsigned short ush;
struct ush4 { ush x, y, z, w; };
struct uint2s { unsigned x, y; };

__device__ inline ush f2bf(float v) {
    union { float f; unsigned u; } c; c.f = v;
    unsigned r = c.u + 0x7FFF + ((c.u >> 16) & 1);
    return (ush)(r >> 16);
}
__device__ inline float bf2f(ush b) {
    union { float f; unsigned u; } c; c.u = ((unsigned)b) << 16; return c.f;
}
__device__ inline f32x4 mfma16(bf16x8 a, bf16x8 b, f32x4 c) {
    return __builtin_amdgcn_mfma_f32_16x16x32_bf16(a, b, c, 0, 0, 0);
}

// ---------------------------------------------------------------------------
__global__ void k_select(const float* __restrict__ logits, int* __restrict__ sel) {
    if (threadIdx.x == 0) {
        float best = logits[0]; int bi = 0;
        for (int i = 1; i < 4; ++i) { float v = logits[i]; if (v > best) { best = v; bi = i; } }
        *sel = bi;
    }
}

// ---------------------------------------------------------------------------
// fused prep (coalesced transposes via LDS tiles). Region map:
//   [0,    1024): x+pe -> bf16 hi/lo, float4-vectorized
//   [1024, 1792): wqkv transpose, 64x64 LDS tiles
//   [1792, 2048): wo transpose, 64x64 LDS tiles
// ---------------------------------------------------------------------------
template<int D>
__device__ void prep_wt_tile(int bT, int tid, const float* __restrict__ w,
                             ush* __restrict__ wh, ush* __restrict__ wl,
                             float (*lds)[65]) {
    constexpr int ds = DM_ / D;
    constexpr int tpr = 3 * ds / 64;
    constexpr int tpc = ds / 64;
    constexpr int tpd = tpr * tpc;
    if (bT >= D * tpd) return;
    const int d = bT / tpd, rem = bT % tpd;
    const int tr = rem / tpr, tc = rem % tpr;
    const float* src = w + (size_t)d * ds * 3 * ds;
    ush* dsth = wh + (size_t)d * 3 * ds * ds;
    ush* dstl = wl + (size_t)d * 3 * ds * ds;
    const int c = tid & 63, r0 = tid >> 6;
    #pragma unroll
    for (int j = 0; j < 16; ++j) {
        const int r = j * 4 + r0;
        lds[r][c] = src[(size_t)(tr * 64 + r) * (3 * ds) + tc * 64 + c];
    }
    __syncthreads();
    #pragma unroll
    for (int j = 0; j < 16; ++j) {
        const int r = j * 4 + r0;
        const float v = lds[c][r];
        const size_t o = (size_t)(tc * 64 + r) * ds + tr * 64 + c;
        const ush h = f2bf(v);
        dsth[o] = h; dstl[o] = f2bf(v - bf2f(h));
    }
}
__global__ __launch_bounds__(256) void k_prep(
        const int* __restrict__ sel, const float* __restrict__ x,
        const float* __restrict__ pe0, const float* __restrict__ pe1,
        const float* __restrict__ pe2, const float* __restrict__ pe3,
        const float* __restrict__ w0, const float* __restrict__ w1,
        const float* __restrict__ w2, const float* __restrict__ w3,
        const float* __restrict__ wo0, const float* __restrict__ wo1,
        const float* __restrict__ wo2, const float* __restrict__ wo3,
        ush* __restrict__ xh, ush* __restrict__ xl,
        ush* __restrict__ wqh, ush* __restrict__ wql,
        ush* __restrict__ woh, ush* __restrict__ wol) {
    __shared__ float lds[64][65];
    const int s = *sel;
    const int bid = blockIdx.x, tid = threadIdx.x;
    if (bid < 1024) {
        const float* pe = (s == 0) ? pe0 : (s == 1) ? pe1 : (s == 2) ? pe2 : pe3;
        const size_t i0 = ((size_t)bid * 256 + tid) * 4;
        const float4 xv = *(const float4*)&x[i0];
        const float4 pv = *(const float4*)&pe[i0 & ((size_t)N_ * DM_ - 1)];
        ush4 h4, l4;
        float v;
        v = xv.x + pv.x; h4.x = f2bf(v); l4.x = f2bf(v - bf2f(h4.x));
        v = xv.y + pv.y; h4.y = f2bf(v); l4.y = f2bf(v - bf2f(h4.y));
        v = xv.z + pv.z; h4.z = f2bf(v); l4.z = f2bf(v - bf2f(h4.z));
        v = xv.w + pv.w; h4.w = f2bf(v); l4.w = f2bf(v - bf2f(h4.w));
        *(ush4*)&xh[i0] = h4;
        *(ush4*)&xl[i0] = l4;
    } else if (bid < 1792) {
        const int bT = bid - 1024;
        switch (s) {
            case 0: prep_wt_tile<1>(bT, tid, w0, wqh, wql, lds); break;
            case 1: prep_wt_tile<2>(bT, tid, w1, wqh, wql, lds); break;
            case 2: prep_wt_tile<4>(bT, tid, w2, wqh, wql, lds); break;
            case 3: prep_wt_tile<8>(bT, tid, w3, wqh, wql, lds); break;
        }
    } else {
        const float* w = (s == 0) ? wo0 : (s == 1) ? wo1 : (s == 2) ? wo2 : wo3;
        const int bT = bid - 1792;
        const int tr = bT >> 4, tc = bT & 15;
        const int c = tid & 63, r0 = tid >> 6;
        #pragma unroll
        for (int j = 0; j < 16; ++j) {
            const int r = j * 4 + r0;
            lds[r][c] = w[(size_t)(tr * 64 + r) * DM_ + tc * 64 + c];
        }
        __syncthreads();
        #pragma unroll
        for (int j = 0; j < 16; ++j) {
            const int r = j * 4 + r0;
            const float v = lds[c][r];
            const size_t o = (size_t)(tc * 64 + r) * DM_ + tr * 64 + c;
            const ush h = f2bf(v);
            woh[o] = h; wol[o] = f2bf(v - bf2f(h));
        }
    }
}

// ---------------------------------------------------------------------------
// Split-bf16 MFMA GEMM core (64x64 tile, BK=32, 4 waves) — used by k_qkv
// ---------------------------------------------------------------------------
template<int KD>
__device__ void gemm_core(const ush* __restrict__ Ah, const ush* __restrict__ Al, int lda,
                          const ush* __restrict__ Bh, const ush* __restrict__ Bl, int ldb,
                          int row0, int col0, int tid, ush* lds, f32x4 acc[2][2]) {
    ush* lAh = lds; ush* lAl = lds + 2560; ush* lBh = lds + 5120; ush* lBl = lds + 7680;
    const int srow = tid >> 2, scg = tid & 3;
    const int lane = tid & 63, w = tid >> 6;
    const int wm = w >> 1, wn = w & 1;
    const int lr = lane & 15, lb = lane >> 4;

    for (int k0 = 0; k0 < KD; k0 += 32) {
        *(bf16x8*)&lAh[srow * 40 + scg * 8] =
            *(const bf16x8*)&Ah[(size_t)(row0 + srow) * lda + k0 + scg * 8];
        *(bf16x8*)&lAl[srow * 40 + scg * 8] =
            *(const bf16x8*)&Al[(size_t)(row0 + srow) * lda + k0 + scg * 8];
        *(bf16x8*)&lBh[srow * 40 + scg * 8] =
            *(const bf16x8*)&Bh[(size_t)(col0 + srow) * ldb + k0 + scg * 8];
        *(bf16x8*)&lBl[srow * 40 + scg * 8] =
            *(const bf16x8*)&Bl[(size_t)(col0 + srow) * ldb + k0 + scg * 8];
        __syncthreads();
        bf16x8 ah[2], al[2], bh[2], bl[2];
        #pragma unroll
        for (int mg = 0; mg < 2; ++mg) {
            const int r = wm * 32 + mg * 16 + lr;
            ah[mg] = *(const bf16x8*)&lAh[r * 40 + lb * 8];
            al[mg] = *(const bf16x8*)&lAl[r * 40 + lb * 8];
        }
        #pragma unroll
        for (int ng = 0; ng < 2; ++ng) {
            const int r = wn * 32 + ng * 16 + lr;
            bh[ng] = *(const bf16x8*)&lBh[r * 40 + lb * 8];
            bl[ng] = *(const bf16x8*)&lBl[r * 40 + lb * 8];
        }
        #pragma unroll
        for (int mg = 0; mg < 2; ++mg)
            #pragma unroll
            for (int ng = 0; ng < 2; ++ng) {
                acc[mg][ng] = mfma16(ah[mg], bh[ng], acc[mg][ng]);
                acc[mg][ng] = mfma16(al[mg], bh[ng], acc[mg][ng]);
                acc[mg][ng] = mfma16(ah[mg], bl[ng], acc[mg][ng]);
            }
        __syncthreads();
    }
}

// ---------------------------------------------------------------------------
// qkv GEMM; epilogue: Q,K bf16 hi/lo [head][n][hd]; V TRANSPOSED bf16 hi/lo
// ---------------------------------------------------------------------------
template<int D>
__device__ void qkv_body(int bid, int tid,
                         const ush* __restrict__ xh, const ush* __restrict__ xl,
                         const ush* __restrict__ wh, const ush* __restrict__ wl,
                         ush* __restrict__ Qh, ush* __restrict__ Ql,
                         ush* __restrict__ Kh, ush* __restrict__ Kl,
                         ush* __restrict__ Vth, ush* __restrict__ Vtl, ush* lds) {
    constexpr int ds = DM_ / D;
    constexpr int hd = ds / H_;
    constexpr int nx = 3 * ds / 64;
    const int bx = bid % nx, by = (bid / nx) & 7, bz = bid / (nx * 8);
    const int b = bz / D, d = bz % D;
    const int row0 = by * 64, col0 = bx * 64;

    f32x4 acc[2][2] = {};
    gemm_core<ds>(xh + (size_t)b * N_ * DM_ + d * ds, xl + (size_t)b * N_ * DM_ + d * ds, DM_,
                  wh + (size_t)d * 3 * ds * ds, wl + (size_t)d * 3 * ds * ds, ds,
                  row0, col0, tid, lds, acc);

    const int lane = tid & 63, w = tid >> 6;
    const int wm = w >> 1, wn = w & 1;
    const int lr = lane & 15, lb = lane >> 4;
    #pragma unroll
    for (int mg = 0; mg < 2; ++mg)
        #pragma unroll
        for (int ng = 0; ng < 2; ++ng) {
            const int n0 = row0 + wm * 32 + mg * 16 + lb * 4;
            const int e  = col0 + wn * 32 + ng * 16 + lr;
            const int part = e / ds, ep = e % ds;
            const int h = ep / hd, t = ep % hd;
            const size_t head = ((size_t)b * D + d) * H_ + h;
            if (part == 2) {
                ush4 h4, l4;
                const float v0 = acc[mg][ng][0], v1 = acc[mg][ng][1];
                const float v2 = acc[mg][ng][2], v3 = acc[mg][ng][3];
                h4.x = f2bf(v0); l4.x = f2bf(v0 - bf2f(h4.x));
                h4.y = f2bf(v1); l4.y = f2bf(v1 - bf2f(h4.y));
                h4.z = f2bf(v2); l4.z = f2bf(v2 - bf2f(h4.z));
                h4.w = f2bf(v3); l4.w = f2bf(v3 - bf2f(h4.w));
                const size_t o = (head * hd + t) * N_ + n0;
                *(ush4*)&Vth[o] = h4;
                *(ush4*)&Vtl[o] = l4;
            } else {
                #pragma unroll
                for (int i = 0; i < 4; ++i) {
                    const size_t o = (head * N_ + n0 + i) * hd + t;
                    const float v = acc[mg][ng][i];
                    const ush hh = f2bf(v), ll = f2bf(v - bf2f(hh));
                    if (part == 0) { Qh[o] = hh; Ql[o] = ll; }
                    else           { Kh[o] = hh; Kl[o] = ll; }
                }
            }
        }
}
__global__ __launch_bounds__(256) void k_qkv(
        const int* __restrict__ sel,
        const ush* __restrict__ xh, const ush* __restrict__ xl,
        const ush* __restrict__ wh, const ush* __restrict__ wl,
        ush* __restrict__ Qh, ush* __restrict__ Ql,
        ush* __restrict__ Kh, ush* __restrict__ Kl,
        ush* __restrict__ Vth, ush* __restrict__ Vtl) {
    __shared__ ush lds[4 * 2560];
    const int bid = blockIdx.x, tid = threadIdx.x;
    switch (*sel) {
        case 0: qkv_body<1>(bid, tid, xh, xl, wh, wl, Qh, Ql, Kh, Kl, Vth, Vtl, lds); break;
        case 1: qkv_body<2>(bid, tid, xh, xl, wh, wl, Qh, Ql, Kh, Kl, Vth, Vtl, lds); break;
        case 2: qkv_body<4>(bid, tid, xh, xl, wh, wl, Qh, Ql, Kh, Kl, Vth, Vtl, lds); break;
        case 3: qkv_body<8>(bid, tid, xh, xl, wh, wl, Qh, Ql, Kh, Kl, Vth, Vtl, lds); break;
    }
}

// ---------------------------------------------------------------------------
// MFMA attention v5: ONE WAVE per block (64 threads), 16 q-rows, all 512
// k-cols in 4 flash passes of 128 (m=0 so l just accumulates; P LDS buffer
// reused each pass). Zero barriers, zero cross-wave traffic; l redistributed
// by shfl. Swapped QK^T, packed cvt_pk P, rounded-P denominator.
// ---------------------------------------------------------------------------
template<int D>
__device__ void attn_body(int bid, int tid,
        const ush* __restrict__ Qh, const ush* __restrict__ Ql,
        const ush* __restrict__ Kh, const ush* __restrict__ Kl,
        const ush* __restrict__ Vth, const ush* __restrict__ Vtl,
        float* __restrict__ O, ush* P) {
    constexpr int ds = DM_ / D, hd = ds / H_;
    constexpr int CH = (hd >= 64) ? 2 : 1;
    constexpr int NT = (hd >= 16) ? hd / 16 : 1;
    constexpr int NB = B_ * D * H_ * 32;   // one wave per 16 q-rows
    if (bid >= NB) return;
    const int bidr = (bid & 7) * (NB / 8) + (bid >> 3);
    const int head = bidr >> 5, qt = bidr & 31;
    const int h = head % H_, d = (head / H_) % D, b = head / (H_ * D);
    const int q0 = qt * 16;
    const size_t hb = (size_t)head * N_ * hd;
    const int lr = tid & 15, lb = tid >> 4;
    const float L2E = 1.44269504f;
    const float SC  = rsqrtf((float)hd) * L2E;
    const float RB2 = LAM_ * (2.0f / N_) * L2E;
    const bf16x8 z8 = {0, 0, 0, 0, 0, 0, 0, 0};

    // Q fragment (B-operand): lane holds q-row q0+lr, k-slice lb*8
    bf16x8 qah[CH], qal[CH];
    #pragma unroll
    for (int c = 0; c < CH; ++c) {
        const int k0 = c * 32 + lb * 8;
        bf16x8 vh = z8, vl = z8;
        if (k0 < hd) {
            const size_t o = hb + (size_t)(q0 + lr) * hd + k0;
            vh = *(const bf16x8*)&Qh[o];
            vl = *(const bf16x8*)&Ql[o];
        }
        qah[c] = vh; qal[c] = vl;
    }

    const int q = q0 + lr;
    float ls = 0.f;
    f32x4 acc2[NT];
    #pragma unroll
    for (int tt = 0; tt < NT; ++tt) acc2[tt] = (f32x4){0.f, 0.f, 0.f, 0.f};

    for (int pass = 0; pass < 4; ++pass) {
        const int col0 = pass * 128;

        // S^T = K Q^T over this pass's 128 cols
        f32x4 s[8];
        #pragma unroll
        for (int t = 0; t < 8; ++t) {
            const int kj0 = col0 + t * 16;
            f32x4 acc = {0.f, 0.f, 0.f, 0.f};
            #pragma unroll
            for (int c = 0; c < CH; ++c) {
                const int k0 = c * 32 + lb * 8;
                bf16x8 kh8 = z8, kl8 = z8;
                if (k0 < hd) {
                    const size_t o = hb + (size_t)(kj0 + lr) * hd + k0;
                    kh8 = *(const bf16x8*)&Kh[o];
                    kl8 = *(const bf16x8*)&Kl[o];
                }
                acc = mfma16(kh8, qah[c], acc);
                acc = mfma16(kl8, qah[c], acc);
                acc = mfma16(kh8, qal[c], acc);
            }
            s[t] = acc;
        }

        // bias + exp2 + packed bf16 P (8B store per tile) + rounded row sum
        #pragma unroll
        for (int t = 0; t < 8; ++t) {
            const int kbase = col0 + t * 16 + lb * 4;
            float p[4];
            #pragma unroll
            for (int i = 0; i < 4; ++i) {
                int dd = q - (kbase + i); dd = dd < 0 ? -dd : dd;
                const int ring = (dd < N_ - dd) ? dd : (N_ - dd);
                p[i] = exp2f(s[t][i] * SC - RB2 * (float)ring);
            }
            unsigned pk0, pk1;
            asm("v_cvt_pk_bf16_f32 %0, %1, %2" : "=v"(pk0) : "v"(p[0]), "v"(p[1]));
            asm("v_cvt_pk_bf16_f32 %0, %1, %2" : "=v"(pk1) : "v"(p[2]), "v"(p[3]));
            union { unsigned u; float f; } c0, c1, c2, c3;
            c0.u = pk0 << 16; c1.u = pk0 & 0xffff0000u;
            c2.u = pk1 << 16; c3.u = pk1 & 0xffff0000u;
            ls += (c0.f + c1.f) + (c2.f + c3.f);
            const int off = ((lr << 8) + ((t * 16 + lb * 4) << 1)) ^ ((lr & 7) << 4);
            uint2s pv; pv.x = pk0; pv.y = pk1;
            *(uint2s*)((char*)P + off) = pv;
        }

        // PV over this pass's 128 cols (wave lockstep: no barrier, compiler
        // inserts lgkmcnt for the ds_write -> ds_read dependency)
        #pragma unroll
        for (int jc = 0; jc < 4; ++jc) {
            int poff = ((lr << 8) + ((jc * 32 + lb * 8) << 1)) ^ ((lr & 7) << 4);
            const bf16x8 pa = *(const bf16x8*)((const char*)P + poff);
            #pragma unroll
            for (int tt = 0; tt < NT; ++tt) {
                const size_t o = hb + (size_t)(tt * 16 + lr) * N_ + col0 + jc * 32 + lb * 8;
                const bf16x8 vh8 = *(const bf16x8*)&Vth[o];
                const bf16x8 vl8 = *(const bf16x8*)&Vtl[o];
                acc2[tt] = mfma16(pa, vh8, acc2[tt]);
                acc2[tt] = mfma16(pa, vl8, acc2[tt]);
            }
        }
    }

    // full row sums: combine the 4 lb-groups sharing q-row lr, then
    // redistribute so output row lb*4+i gets l[lb*4+i]
    ls += __shfl_xor(ls, 16);
    ls += __shfl_xor(ls, 32);
    float linv[4];
    #pragma unroll
    for (int i = 0; i < 4; ++i) linv[i] = 1.0f / __shfl(ls, lb * 4 + i);

    #pragma unroll
    for (int tt = 0; tt < NT; ++tt)
        #pragma unroll
        for (int i = 0; i < 4; ++i) {
            const int rn = q0 + lb * 4 + i;
            const int tc = tt * 16 + lr;
            if (tc < hd)
                O[((size_t)b * N_ + rn) * DM_ + d * ds + h * hd + tc] = acc2[tt][i] * linv[i];
        }
}
__global__ __launch_bounds__(64) void k_attn(
        const int* __restrict__ sel,
        const ush* __restrict__ Qh, const ush* __restrict__ Ql,
        const ush* __restrict__ Kh, const ush* __restrict__ Kl,
        const ush* __restrict__ Vth, const ush* __restrict__ Vtl,
        float* __restrict__ O) {
    __shared__ __align__(16) ush P[16 * 128];   // 4 KB, wave-private
    const int bid = blockIdx.x, tid = threadIdx.x;
    switch (*sel) {
        case 0: attn_body<1>(bid, tid, Qh, Ql, Kh, Kl, Vth, Vtl, O, P); break;
        case 1: attn_body<2>(bid, tid, Qh, Ql, Kh, Kl, Vth, Vtl, O, P); break;
        case 2: attn_body<4>(bid, tid, Qh, Ql, Kh, Kl, Vth, Vtl, O, P); break;
        case 3: attn_body<8>(bid, tid, Qh, Ql, Kh, Kl, Vth, Vtl, O, P); break;
    }
}

// ---------------------------------------------------------------------------
// depth mix: F = einsum(mix, O) -> bf16 hi/lo
// ---------------------------------------------------------------------------
template<int D>
__device__ void mix_body(int bid, int tid, const float* __restrict__ fu,
                         const float* __restrict__ fv, const float* __restrict__ O,
                         ush* __restrict__ Fh, ush* __restrict__ Fl, float* mixs) {
    constexpr int ds = DM_ / D;
    constexpr int R = (D / 4 > 0) ? (D / 4) : 1;
    if (tid < D * D) {
        const int d = tid / D, f = tid % D;
        float m = 0.f;
        #pragma unroll
        for (int rr = 0; rr < R; ++rr) m += fu[d * R + rr] * fv[rr * D + f];
        mixs[tid] = m;
    }
    __syncthreads();
    const size_t idx = (size_t)bid * 256 + tid;
    const int dm = (int)(idx % DM_);
    const size_t bn = idx / DM_;
    const int d = dm / ds, s0 = dm % ds;
    const float* Ob = O + bn * DM_ + s0;
    float acc = 0.f;
    #pragma unroll
    for (int f = 0; f < D; ++f) acc += mixs[d * D + f] * Ob[(size_t)f * ds];
    const ush hh = f2bf(acc);
    Fh[idx] = hh; Fl[idx] = f2bf(acc - bf2f(hh));
}
__global__ __launch_bounds__(256) void k_mix(
        const int* __restrict__ sel,
        const float* __restrict__ fu0, const float* __restrict__ fv0,
        const float* __restrict__ fu1, const float* __restrict__ fv1,
        const float* __restrict__ fu2, const float* __restrict__ fv2,
        const float* __restrict__ fu3, const float* __restrict__ fv3,
        const float* __restrict__ O, ush* __restrict__ Fh, ush* __restrict__ Fl) {
    __shared__ float mixs[64];
    const int bid = blockIdx.x, tid = threadIdx.x;
    switch (*sel) {
        case 0: mix_body<1>(bid, tid, fu0, fv0, O, Fh, Fl, mixs); break;
        case 1: mix_body<2>(bid, tid, fu1, fv1, O, Fh, Fl, mixs); break;
        case 2: mix_body<4>(bid, tid, fu2, fv2, O, Fh, Fl, mixs); break;
        case 3: mix_body<8>(bid, tid, fu3, fv3, O, Fh, Fl, mixs); break;
    }
}

// ---------------------------------------------------------------------------
// out = F @ wo — 32x64 tiles, grid 512
// ---------------------------------------------------------------------------
__global__ __launch_bounds__(256) void k_wo(
        const ush* __restrict__ Fh, const ush* __restrict__ Fl,
        const ush* __restrict__ wh, const ush* __restrict__ wl,
        float* __restrict__ out) {
    __shared__ ush lA[2][32 * 40];
    __shared__ ush lB[2][64 * 40];
    const int tid = threadIdx.x;
    const int bx = blockIdx.x & 15, by = blockIdx.x >> 4;
    const int row0 = by * 32, col0 = bx * 64;
    const int lane = tid & 63, w = tid >> 6;
    const int wq = w >> 1, wn = w & 1;
    const int lr = lane & 15, lb = lane >> 4;
    f32x4 acc[2] = {};

    for (int k0 = 0; k0 < DM_; k0 += 32) {
        {
            const int half = tid >> 7, t2 = tid & 127;
            const int srow = t2 >> 2, scg = t2 & 3;
            const ush* src = half ? Fl : Fh;
            *(bf16x8*)&lA[half][srow * 40 + scg * 8] =
                *(const bf16x8*)&src[(size_t)(row0 + srow) * DM_ + k0 + scg * 8];
        }
        {
            const int srow = tid >> 2, scg = tid & 3;
            *(bf16x8*)&lB[0][srow * 40 + scg * 8] =
                *(const bf16x8*)&wh[(size_t)(col0 + srow) * DM_ + k0 + scg * 8];
            *(bf16x8*)&lB[1][srow * 40 + scg * 8] =
                *(const bf16x8*)&wl[(size_t)(col0 + srow) * DM_ + k0 + scg * 8];
        }
        __syncthreads();
        const int ar = wq * 16 + lr;
        const bf16x8 ah = *(const bf16x8*)&lA[0][ar * 40 + lb * 8];
        const bf16x8 al = *(const bf16x8*)&lA[1][ar * 40 + lb * 8];
        #pragma unroll
        for (int ng = 0; ng < 2; ++ng) {
            const int br = wn * 32 + ng * 16 + lr;
            const bf16x8 bh = *(const bf16x8*)&lB[0][br * 40 + lb * 8];
            const bf16x8 bl = *(const bf16x8*)&lB[1][br * 40 + lb * 8];
            acc[ng] = mfma16(ah, bh, acc[ng]);
            acc[ng] = mfma16(al, bh, acc[ng]);
            acc[ng] = mfma16(ah, bl, acc[ng]);
        }
        __syncthreads();
    }
    #pragma unroll
    for (int ng = 0; ng < 2; ++ng)
        #pragma unroll
        for (int i = 0; i < 4; ++i) {
            const int r = row0 + wq * 16 + lb * 4 + i;
            const int c = col0 + wn * 32 + ng * 16 + lr;
            out[(size_t)r * DM_ + c] = acc[ng][i];
        }
}

// ---------------------------------------------------------------------------
extern "C" void kernel_launch(void* const* d_in, const int* in_sizes, int n_in,
                              void* d_out, int out_size, void* d_ws, size_t ws_size,
                              hipStream_t stream) {
    const float* x      = (const float*)d_in[0];
    const float* logits = (const float*)d_in[1];
    float* out = (float*)d_out;

    char* p = (char*)d_ws;
    int* sel = (int*)p; p += 256;
    const size_t MB = 1024 * 1024;
    ush* Qh = (ush*)p; p += 2 * MB;
    ush* Ql = (ush*)p; p += 2 * MB;
    ush* Kh = (ush*)p; p += 2 * MB;
    ush* Kl = (ush*)p; p += 2 * MB;
    ush* Vth = (ush*)p; p += 2 * MB + 65536;   // pad: hd=8 garbage-row reads
    ush* Vtl = (ush*)p; p += 2 * MB + 65536;
    float* O = (float*)p; p += 4 * MB;
    ush* xh = (ush*)p; p += 2 * MB;
    ush* xl = (ush*)p; p += 2 * MB;
    ush* wqh = (ush*)p; p += 6 * MB;
    ush* wql = (ush*)p; p += 6 * MB;
    ush* woh = (ush*)p; p += 2 * MB;
    ush* wol = (ush*)p; p += 2 * MB;
    ush* Fh = xh, *Fl = xl;   // k_mix writes after k_qkv consumed xh/xl

    k_select<<<1, 64, 0, stream>>>(logits, sel);
    k_prep<<<dim3(2048), dim3(256), 0, stream>>>(
        sel, x,
        (const float*)d_in[2], (const float*)d_in[7],
        (const float*)d_in[12], (const float*)d_in[17],
        (const float*)d_in[3], (const float*)d_in[8],
        (const float*)d_in[13], (const float*)d_in[18],
        (const float*)d_in[4], (const float*)d_in[9],
        (const float*)d_in[14], (const float*)d_in[19],
        xh, xl, wqh, wql, woh, wol);
    k_qkv<<<dim3(768), dim3(256), 0, stream>>>(sel, xh, xl, wqh, wql,
                                               Qh, Ql, Kh, Kl, Vth, Vtl);
    k_attn<<<dim3(8192), dim3(64), 0, stream>>>(sel, Qh, Ql, Kh, Kl, Vth, Vtl, O);
    k_mix<<<dim3(B_ * N_ * DM_ / 256), dim3(256), 0, stream>>>(
        sel,
        (const float*)d_in[5],  (const float*)d_in[6],
        (const float*)d_in[10], (const float*)d_in[11],
        (const float*)d_in[15], (const float*)d_in[16],
        (const float*)d_in[20], (const float*)d_in[21],
        O, Fh, Fl);
    k_wo<<<dim3(512), dim3(256), 0, stream>>>(Fh, Fl, woh, wol, out);
}